// Round 2
// baseline (1482.903 us; speedup 1.0000x reference)
//
#include <hip/hip_runtime.h>

#define NN 100000
#define NE 1600000
#define NTILE_E (NE / 128)      // 12500, exact
#define NTILE_N 782             // ceil(100000/128)

typedef __attribute__((ext_vector_type(4))) float f32x4;
typedef __attribute__((ext_vector_type(8))) short s16x8;

__device__ __forceinline__ unsigned short f2bf(float f) {
  unsigned u = __builtin_bit_cast(unsigned, f);
  u = (u + 0x7FFFu + ((u >> 16) & 1u)) >> 16;
  return (unsigned short)u;
}
__device__ __forceinline__ void pack4(float4 v, unsigned short* dst) {
  ushort4 h;
  h.x = f2bf(v.x); h.y = f2bf(v.y); h.z = f2bf(v.z); h.w = f2bf(v.w);
  *(ushort4*)dst = h;
}

// ---------------------------------------------------------------- K0: weight prep
__global__ void k0_prep(const float* __restrict__ W1, const float* __restrict__ W3,
                        unsigned short* __restrict__ W1bT, unsigned short* __restrict__ W3bT) {
  int i = blockIdx.x * 256 + threadIdx.x;
  if (i < 16384) {
    int n = i >> 7, k = i & 127;
    W1bT[i] = f2bf(W1[k * 128 + n]);
  } else if (i < 16384 + 24576) {
    int j = i - 16384;
    int n = j / 192, k = j % 192;
    W3bT[j] = f2bf(W3[k * 128 + n]);
  }
}

// ---------------------------------------------------------------- sort: histogram
__global__ void k_hist(const int* __restrict__ eidx, int* __restrict__ hist) {
  int e = blockIdx.x * 256 + threadIdx.x;
  if (e < NE) atomicAdd(&hist[eidx[NE + e]], 1);
}

// ---------------------------------------------------------------- sort: scan (1 block)
__global__ void k_scan(int* __restrict__ hist, float* __restrict__ cntF) {
  __shared__ int ssum[1024];
  const int t = threadIdx.x;
  const int base = t * 98;                       // 1024*98 = 100352 >= NN
  const int cl = (base >= NN) ? 0 : ((NN - base < 98) ? (NN - base) : 98);
  int s = 0;
  for (int i = 0; i < cl; i++) s += hist[base + i];
  ssum[t] = s;
  __syncthreads();
  for (int d = 1; d < 1024; d <<= 1) {
    int v = (t >= d) ? ssum[t - d] : 0;
    __syncthreads();
    ssum[t] += v;
    __syncthreads();
  }
  int run = (t == 0) ? 0 : ssum[t - 1];
  for (int i = 0; i < cl; i++) {
    int hv = hist[base + i];
    hist[base + i] = run;                        // exclusive offsets, in place
    cntF[base + i] = (float)hv;
    run += hv;
  }
}

// ---------------------------------------------------------------- sort: scatter
__global__ void k_scatter(const int* __restrict__ eidx, int* __restrict__ off,
                          int2* __restrict__ pairS) {
  int e = blockIdx.x * 256 + threadIdx.x;
  if (e < NE) {
    int c = eidx[NE + e];
    int p = atomicAdd(&off[c], 1);
    pairS[p] = make_int2(c, e);
  }
}

// ---------------------------------------------------------------- K1: edge pass (sorted)
// 512 threads / 8 waves, each owns a 32x64 quadrant (acc[2][4]).
// Register budget for 16 waves/CU (4 waves/SIMD, unified VGPR+AGPR <= 128):
//   bf[4][2]=32V (two K-phases, reloaded from L1-resident W1bT each tile; base
//   pointer laundered via asm so LICM can't hoist the loads) + acc 32A + af 8V
//   + misc ~30V ~= 112. launch_bounds(512,2) so the allocator is NOT capped at
//   64 VGPRs (round-1's (512,4) forced 64 -> ~45 spilled regs -> +800 MB of
//   scratch HBM traffic, the measured regression).
__global__ __launch_bounds__(512, 2) void k1_edge(
    const float* __restrict__ x, const int* __restrict__ eidx,
    const float* __restrict__ ea, const unsigned short* __restrict__ W1bT,
    const float* __restrict__ b1, const int2* __restrict__ pairS,
    float* __restrict__ S, float* __restrict__ stat1) {
  __shared__ __align__(16) char HAt[67584];      // H f32[128][132]; At ushort[128][136] aliases
  __shared__ int rIdxS[128];
  __shared__ int eIdxS[128];
  __shared__ int colT[132];    // colT[i+1] = dest node of local row i; [0]/[129] halos
  __shared__ float sred[256];
  unsigned short (*At)[136] = (unsigned short (*)[136])HAt;
  float (*H)[132] = (float (*)[132])HAt;

  const int tid = threadIdx.x;
  const int wave = tid >> 6, lane = tid & 63;
  const int l15 = lane & 15, quad = lane >> 4;
  const int rowbase = (wave >> 1) * 32;          // 4 row-groups of 32
  const int colbase = (wave & 1) * 64;           // 2 col-halves

  float b1j[4];
#pragma unroll
  for (int ct = 0; ct < 4; ct++) b1j[ct] = b1[colbase + ct * 16 + l15];

  float lsum[4] = {0, 0, 0, 0}, lsq[4] = {0, 0, 0, 0};

  for (int tile = blockIdx.x; tile < NTILE_E; tile += gridDim.x) {
    const int eb = tile * 128;
    __syncthreads();   // previous iteration's walk readers done (H region free)
    if (tid < 128) {
      int2 pr = pairS[eb + tid];
      eIdxS[tid] = pr.y;
      rIdxS[tid] = eidx[pr.y];
      colT[tid + 1] = pr.x;
    } else if (tid == 128) {
      colT[0] = (eb > 0) ? pairS[eb - 1].x : -1;
    } else if (tid == 129) {
      colT[129] = (eb + 128 < NE) ? pairS[eb + 128].x : -1;
    }
    __syncthreads();
#pragma unroll
    for (int i = 0; i < 4; i++) {
      int idx = tid + i * 512; int e = idx >> 4, c = idx & 15;
      float4 v = ((const float4*)x)[(size_t)rIdxS[e] * 16 + c];
      pack4(v, &At[e][c * 4]);
    }
#pragma unroll
    for (int i = 0; i < 4; i++) {
      int idx = tid + i * 512; int e = idx >> 4, c = idx & 15;
      float4 v = ((const float4*)ea)[(size_t)eIdxS[e] * 16 + c];
      pack4(v, &At[e][64 + c * 4]);
    }
    __syncthreads();

    f32x4 acc[2][4];
#pragma unroll
    for (int rt = 0; rt < 2; rt++)
#pragma unroll
      for (int ct = 0; ct < 4; ct++) acc[rt][ct] = (f32x4){0.f, 0.f, 0.f, 0.f};

    // laundered base: compiler cannot prove loads below are tile-invariant,
    // so bf[][] stays a 32-reg working set instead of a 64-reg resident array
    unsigned woff = 0;
    asm volatile("" : "+v"(woff));
    const unsigned short* W1v = W1bT + woff;

#pragma unroll
    for (int half = 0; half < 2; half++) {
      s16x8 bf[4][2];
#pragma unroll
      for (int ct = 0; ct < 4; ct++)
#pragma unroll
        for (int j = 0; j < 2; j++)
          bf[ct][j] = *(const s16x8*)(W1v + (colbase + ct * 16 + l15) * 128 + (half * 2 + j) * 32 + quad * 8);
#pragma unroll
      for (int j = 0; j < 2; j++) {
        s16x8 af[2];
#pragma unroll
        for (int rt = 0; rt < 2; rt++)
          af[rt] = *(const s16x8*)&At[rowbase + rt * 16 + l15][(half * 2 + j) * 32 + quad * 8];
#pragma unroll
        for (int rt = 0; rt < 2; rt++)
#pragma unroll
          for (int ct = 0; ct < 4; ct++)
            acc[rt][ct] = __builtin_amdgcn_mfma_f32_16x16x32_bf16(af[rt], bf[ct][j], acc[rt][ct], 0, 0, 0);
      }
    }

    __syncthreads();   // all MFMA reads of At done; safe to overwrite (H aliases At)
    // write post-leaky h1 (f32) to full-width H
#pragma unroll
    for (int rt = 0; rt < 2; rt++)
#pragma unroll
      for (int r = 0; r < 4; r++) {
        const int er = rowbase + rt * 16 + quad * 4 + r;
#pragma unroll
        for (int ct = 0; ct < 4; ct++) {
          float v = acc[rt][ct][r] + b1j[ct];
          v = v > 0.0f ? v : 0.01f * v;
          lsum[ct] += v; lsq[ct] += v * v;
          H[er][colbase + ct * 16 + l15] = v;
        }
      }
    __syncthreads();

    // segmented flush: thread -> (col = tid&127, rows [r0, r0+32)); single pass
    {
      const int col = tid & 127;
      const int r0 = (tid >> 7) * 32;
      float runsum = H[r0][col];
      int runstart = r0;
      int curnode = colT[r0 + 1];
      for (int r = r0 + 1; r < r0 + 32; ++r) {
        int nd = colT[r + 1];
        float v = H[r][col];
        if (nd == curnode) { runsum += v; }
        else {
          float* p = S + (size_t)curnode * 128 + col;
          if (colT[runstart] != curnode) *p = runsum;   // run complete (end change observed)
          else atomicAdd(p, runsum);
          curnode = nd; runsum = v; runstart = r;
        }
      }
      float* p = S + (size_t)curnode * 128 + col;
      if (colT[runstart] != curnode && colT[r0 + 33] != curnode) *p = runsum;
      else atomicAdd(p, runsum);
    }
  }

  if (tid < 256) sred[tid] = 0.0f;
  __syncthreads();
#pragma unroll
  for (int ct = 0; ct < 4; ct++) {
    float s = lsum[ct], q = lsq[ct];
    s += __shfl_down(s, 32); q += __shfl_down(q, 32);
    s += __shfl_down(s, 16); q += __shfl_down(q, 16);
    if (lane < 16) {
      atomicAdd(&sred[colbase + ct * 16 + l15], s);
      atomicAdd(&sred[128 + colbase + ct * 16 + l15], q);
    }
  }
  __syncthreads();
  if (tid < 256) atomicAdd(&stat1[tid], sred[tid]);
}

// ---------------------------------------------------------------- K2: fold BN1 into W2
__global__ void k2_fold1(const float* __restrict__ stat1, const float* __restrict__ g1,
                         const float* __restrict__ be1, const float* __restrict__ W2,
                         const float* __restrict__ b2,
                         unsigned short* __restrict__ W2pT, float* __restrict__ v128) {
  __shared__ float s1s[128], t1s[128];
  __shared__ float red[256];
  const int tid = threadIdx.x;
  if (tid < 128) {
    float mean = stat1[tid] * (1.0f / NE);
    float var = stat1[128 + tid] * (1.0f / NE) - mean * mean;
    float rstd = rsqrtf(var + 1e-5f);
    float s = g1[tid] * rstd;
    s1s[tid] = s; t1s[tid] = be1[tid] - mean * s;
  }
  __syncthreads();
  const int b = blockIdx.x;
  if (b < 16) {
#pragma unroll
    for (int j = 0; j < 4; j++) {
      int i = b * 1024 + j * 256 + tid;          // i indexes W2 [k][n] row-major
      int k = i >> 7, n = i & 127;
      W2pT[n * 128 + k] = f2bf(s1s[k] * W2[i]);
    }
  } else {
    int j = tid & 127, hh = tid >> 7;
    float p = 0.f;
    for (int k = hh * 64; k < hh * 64 + 64; k++) p += t1s[k] * W2[k * 128 + j];
    red[tid] = p;
    __syncthreads();
    if (tid < 128) v128[tid] = red[tid] + red[tid + 128] + b2[tid];
  }
}

// ---------------------------------------------------------------- K3: node pass
// Unified LDS buffer [128][200]: x in cols 0..63, S (then t1) in cols 64..191.
__global__ __launch_bounds__(256, 3) void k3_node(
    const float* __restrict__ x, const float* __restrict__ S, const float* __restrict__ cnt,
    const unsigned short* __restrict__ W2pT, const float* __restrict__ v128,
    const unsigned short* __restrict__ W3bT, const float* __restrict__ b3,
    unsigned short* __restrict__ tOut, float* __restrict__ stat2) {
  __shared__ __align__(16) unsigned short Abuf[128][200];
  __shared__ float cbuf[128];
  __shared__ float sred[256];

  const int tid = threadIdx.x;
  const int wave = tid >> 6, lane = tid & 63;
  const int l15 = lane & 15, quad = lane >> 4;
  const int rowbase = (wave >> 1) * 64;
  const int colbase = (wave & 1) * 64;

  float vj[4], b3j[4];
#pragma unroll
  for (int ct = 0; ct < 4; ct++) {
    int jc = colbase + ct * 16 + l15;
    vj[ct] = v128[jc]; b3j[ct] = b3[jc];
  }
  float lsum[4] = {0, 0, 0, 0}, lsq[4] = {0, 0, 0, 0};

  for (int t = blockIdx.x; t < NTILE_N; t += gridDim.x) {
    const int nb = t * 128;
    __syncthreads();
#pragma unroll
    for (int i = 0; i < 8; i++) {               // x -> cols 0..63
      int idx = tid + i * 256; int e = idx >> 4, c = idx & 15;
      int node = nb + e;
      float4 v = {0.f, 0.f, 0.f, 0.f};
      if (node < NN) v = ((const float4*)x)[(size_t)node * 16 + c];
      pack4(v, &Abuf[e][c * 4]);
    }
#pragma unroll
    for (int i = 0; i < 16; i++) {              // S -> cols 64..191
      int idx = tid + i * 256; int e = idx >> 5, c = idx & 31;
      int node = nb + e;
      float4 v = {0.f, 0.f, 0.f, 0.f};
      if (node < NN) v = ((const float4*)S)[(size_t)node * 32 + c];
      pack4(v, &Abuf[e][64 + c * 4]);
    }
    if (tid < 128) cbuf[tid] = (nb + tid < NN) ? cnt[nb + tid] : 0.0f;
    __syncthreads();

    f32x4 acc[4][4];
#pragma unroll
    for (int rt = 0; rt < 4; rt++)
#pragma unroll
      for (int ct = 0; ct < 4; ct++) acc[rt][ct] = (f32x4){0.f, 0.f, 0.f, 0.f};
#pragma unroll
    for (int ks = 0; ks < 4; ks++) {
      s16x8 af[4];
#pragma unroll
      for (int rt = 0; rt < 4; rt++)
        af[rt] = *(const s16x8*)&Abuf[rowbase + rt * 16 + l15][64 + ks * 32 + quad * 8];
      s16x8 bfr[4];
#pragma unroll
      for (int ct = 0; ct < 4; ct++)
        bfr[ct] = *(const s16x8*)(W2pT + (colbase + ct * 16 + l15) * 128 + ks * 32 + quad * 8);
#pragma unroll
      for (int rt = 0; rt < 4; rt++)
#pragma unroll
        for (int ct = 0; ct < 4; ct++)
          acc[rt][ct] = __builtin_amdgcn_mfma_f32_16x16x32_bf16(af[rt], bfr[ct], acc[rt][ct], 0, 0, 0);
    }
    __syncthreads();
#pragma unroll
    for (int rt = 0; rt < 4; rt++)
#pragma unroll
      for (int r = 0; r < 4; r++) {
        int er = rowbase + rt * 16 + quad * 4 + r;
#pragma unroll
        for (int ct = 0; ct < 4; ct++) {
          float val = acc[rt][ct][r] + cbuf[er] * vj[ct];
          Abuf[er][64 + colbase + ct * 16 + l15] = f2bf(val);   // t1 overwrites S region
        }
      }
    __syncthreads();

    f32x4 acc2[4][4];
#pragma unroll
    for (int rt = 0; rt < 4; rt++)
#pragma unroll
      for (int ct = 0; ct < 4; ct++) acc2[rt][ct] = (f32x4){0.f, 0.f, 0.f, 0.f};
#pragma unroll
    for (int ks = 0; ks < 6; ks++) {            // K=192: cols 0..191 = [x | t1]
      s16x8 af[4];
#pragma unroll
      for (int rt = 0; rt < 4; rt++)
        af[rt] = *(const s16x8*)&Abuf[rowbase + rt * 16 + l15][ks * 32 + quad * 8];
      s16x8 bfr[4];
#pragma unroll
      for (int ct = 0; ct < 4; ct++)
        bfr[ct] = *(const s16x8*)(W3bT + (size_t)(colbase + ct * 16 + l15) * 192 + ks * 32 + quad * 8);
#pragma unroll
      for (int rt = 0; rt < 4; rt++)
#pragma unroll
        for (int ct = 0; ct < 4; ct++)
          acc2[rt][ct] = __builtin_amdgcn_mfma_f32_16x16x32_bf16(af[rt], bfr[ct], acc2[rt][ct], 0, 0, 0);
    }

#pragma unroll
    for (int rt = 0; rt < 4; rt++)
#pragma unroll
      for (int r = 0; r < 4; r++) {
        int er = rowbase + rt * 16 + quad * 4 + r;
        int node = nb + er;
        if (node < NN) {
#pragma unroll
          for (int ct = 0; ct < 4; ct++) {
            float val = acc2[rt][ct][r] + b3j[ct];
            val = val > 0.0f ? val : 0.01f * val;
            lsum[ct] += val; lsq[ct] += val * val;
            tOut[(size_t)node * 128 + colbase + ct * 16 + l15] = f2bf(val);
          }
        }
      }
  }

  sred[tid] = 0.0f;
  __syncthreads();
#pragma unroll
  for (int ct = 0; ct < 4; ct++) {
    float s = lsum[ct], q = lsq[ct];
    s += __shfl_down(s, 32); q += __shfl_down(q, 32);
    s += __shfl_down(s, 16); q += __shfl_down(q, 16);
    if (lane < 16) {
      atomicAdd(&sred[colbase + ct * 16 + l15], s);
      atomicAdd(&sred[128 + colbase + ct * 16 + l15], q);
    }
  }
  __syncthreads();
  atomicAdd(&stat2[tid], sred[tid]);
}

// ---------------------------------------------------------------- K5: fold BN2 into W4
__global__ void k5_fold2(const float* __restrict__ stat2, const float* __restrict__ g2,
                         const float* __restrict__ be2, const float* __restrict__ W4,
                         const float* __restrict__ b4,
                         unsigned short* __restrict__ W4fT, float* __restrict__ b4f) {
  __shared__ float s2s[128], t2s[128];
  __shared__ float red[256];
  const int tid = threadIdx.x;
  if (tid < 128) {
    float mean = stat2[tid] * (1.0f / NN);
    float var = stat2[128 + tid] * (1.0f / NN) - mean * mean;
    float rstd = rsqrtf(var + 1e-5f);
    float s = g2[tid] * rstd;
    s2s[tid] = s; t2s[tid] = be2[tid] - mean * s;
  }
  __syncthreads();
  const int b = blockIdx.x;
  if (b < 8) {
#pragma unroll
    for (int j = 0; j < 4; j++) {
      int i = b * 1024 + j * 256 + tid;          // i indexes W4 [k][n] row-major, n<64
      int k = i >> 6, n = i & 63;
      W4fT[n * 128 + k] = f2bf(s2s[k] * W4[i]);
    }
  } else {
    int j = tid & 63, part = tid >> 6;
    float p = 0.f;
    for (int k = part * 32; k < part * 32 + 32; k++) p += t2s[k] * W4[k * 64 + j];
    red[tid] = p;
    __syncthreads();
    if (tid < 64) b4f[tid] = red[tid] + red[tid + 64] + red[tid + 128] + red[tid + 192] + b4[tid];
  }
}

// ---------------------------------------------------------------- K6: out = t @ W4f + b4f
__global__ __launch_bounds__(256, 4) void k6_out(
    const unsigned short* __restrict__ tIn, const unsigned short* __restrict__ W4fT,
    const float* __restrict__ b4f, float* __restrict__ out) {
  __shared__ unsigned short Abuf[128][136];
  const int tid = threadIdx.x;
  const int wave = tid >> 6, lane = tid & 63;
  const int l15 = lane & 15, quad = lane >> 4;
  const int rowbase = (wave >> 1) * 64;
  const int colbase = (wave & 1) * 32;

  s16x8 bfrag[2][4];
#pragma unroll
  for (int ct = 0; ct < 2; ct++)
#pragma unroll
    for (int ks = 0; ks < 4; ks++)
      bfrag[ct][ks] = *(const s16x8*)(W4fT + (colbase + ct * 16 + l15) * 128 + ks * 32 + quad * 8);
  float bj[2];
#pragma unroll
  for (int ct = 0; ct < 2; ct++) bj[ct] = b4f[colbase + ct * 16 + l15];

  for (int t = blockIdx.x; t < NTILE_N; t += gridDim.x) {
    const int nb = t * 128;
    __syncthreads();
#pragma unroll
    for (int i = 0; i < 8; i++) {
      int idx = tid + i * 256; int e = idx >> 4, c = idx & 15;
      int node = nb + e;
      s16x8 v = {0, 0, 0, 0, 0, 0, 0, 0};
      if (node < NN) v = *(const s16x8*)(tIn + (size_t)node * 128 + c * 8);
      *(s16x8*)&Abuf[e][c * 8] = v;
    }
    __syncthreads();

    f32x4 acc[4][2];
#pragma unroll
    for (int rt = 0; rt < 4; rt++)
#pragma unroll
      for (int ct = 0; ct < 2; ct++) acc[rt][ct] = (f32x4){0.f, 0.f, 0.f, 0.f};
#pragma unroll
    for (int ks = 0; ks < 4; ks++) {
      s16x8 af[4];
#pragma unroll
      for (int rt = 0; rt < 4; rt++)
        af[rt] = *(const s16x8*)&Abuf[rowbase + rt * 16 + l15][ks * 32 + quad * 8];
#pragma unroll
      for (int rt = 0; rt < 4; rt++)
#pragma unroll
        for (int ct = 0; ct < 2; ct++)
          acc[rt][ct] = __builtin_amdgcn_mfma_f32_16x16x32_bf16(af[rt], bfrag[ct][ks], acc[rt][ct], 0, 0, 0);
    }
#pragma unroll
    for (int rt = 0; rt < 4; rt++)
#pragma unroll
      for (int r = 0; r < 4; r++) {
        int er = rowbase + rt * 16 + quad * 4 + r;
        int node = nb + er;
        if (node < NN) {
#pragma unroll
          for (int ct = 0; ct < 2; ct++)
            out[(size_t)node * 64 + colbase + ct * 16 + l15] = acc[rt][ct][r] + bj[ct];
        }
      }
  }
}

// ---------------------------------------------------------------- launch
extern "C" void kernel_launch(void* const* d_in, const int* in_sizes, int n_in,
                              void* d_out, int out_size, void* d_ws, size_t ws_size,
                              hipStream_t stream) {
  (void)in_sizes; (void)n_in; (void)out_size; (void)ws_size;
  const float* x   = (const float*)d_in[0];
  const int*   ei  = (const int*)d_in[1];
  const float* ea  = (const float*)d_in[2];
  const float* W1  = (const float*)d_in[5];
  const float* b1  = (const float*)d_in[6];
  const float* g1  = (const float*)d_in[7];
  const float* be1 = (const float*)d_in[8];
  const float* W2  = (const float*)d_in[9];
  const float* b2  = (const float*)d_in[10];
  const float* W3  = (const float*)d_in[11];
  const float* b3  = (const float*)d_in[12];
  const float* g2  = (const float*)d_in[13];
  const float* be2 = (const float*)d_in[14];
  const float* W4  = (const float*)d_in[15];
  const float* b4  = (const float*)d_in[16];
  float* out = (float*)d_out;

  char* w = (char*)d_ws;
  float* S     = (float*)(w);                              // 51,200,000
  float* stat1 = (float*)(w + 51200000);                   //      1,024
  float* stat2 = (float*)(w + 51201024);                   //      1,024
  int*   hist  = (int*)  (w + 51202048);                   //    400,384  (also off[])
  float* cntF  = (float*)(w + 51602432);                   //    400,384
  unsigned short* W1bT = (unsigned short*)(w + 52002816);  //     32,768
  unsigned short* W3bT = (unsigned short*)(w + 52035584);  //     49,152
  unsigned short* W2pT = (unsigned short*)(w + 52084736);  //     32,768
  float* v128  = (float*)(w + 52117504);                   //        512
  unsigned short* W4fT = (unsigned short*)(w + 52118016);  //     16,384
  float* b4f   = (float*)(w + 52134400);                   //        256
  unsigned short* tOut = (unsigned short*)(w + 52134656);  // 25,600,000
  // pairS (12.8 MB, int2 {col,e}) aliases tOut's space — lifetimes disjoint (sort+k1 vs k3+k6)
  int2* pairS = (int2*)(w + 52134656);                     // 12,800,000
  // total ws use: 77,734,656 B

  hipMemsetAsync(d_ws, 0, 51602432, stream);   // zero S + stat1 + stat2 + hist

  k0_prep<<<160, 256, 0, stream>>>(W1, W3, W1bT, W3bT);
  k_hist<<<6250, 256, 0, stream>>>(ei, hist);
  k_scan<<<1, 1024, 0, stream>>>(hist, cntF);
  k_scatter<<<6250, 256, 0, stream>>>(ei, hist, pairS);
  k1_edge<<<512, 512, 0, stream>>>(x, ei, ea, W1bT, b1, pairS, S, stat1);
  k2_fold1<<<17, 256, 0, stream>>>(stat1, g1, be1, W2, b2, W2pT, v128);
  k3_node<<<512, 256, 0, stream>>>(x, S, cntF, W2pT, v128, W3bT, b3, tOut, stat2);
  k5_fold2<<<9, 256, 0, stream>>>(stat2, g2, be2, W4, b4, W4fT, b4f);
  k6_out<<<512, 256, 0, stream>>>(tOut, W4fT, b4f, out);
}

// Round 3
// 1318.771 us; speedup vs baseline: 1.1245x; 1.1245x over previous
//
#include <hip/hip_runtime.h>

#define NN 100000
#define NE 1600000
#define NTILE_E (NE / 128)      // 12500, exact
#define NTILE_N 782             // ceil(100000/128)

typedef __attribute__((ext_vector_type(4))) float f32x4;
typedef __attribute__((ext_vector_type(8))) short s16x8;

__device__ __forceinline__ unsigned short f2bf(float f) {
  unsigned u = __builtin_bit_cast(unsigned, f);
  u = (u + 0x7FFFu + ((u >> 16) & 1u)) >> 16;
  return (unsigned short)u;
}
__device__ __forceinline__ void pack4(float4 v, unsigned short* dst) {
  ushort4 h;
  h.x = f2bf(v.x); h.y = f2bf(v.y); h.z = f2bf(v.z); h.w = f2bf(v.w);
  *(ushort4*)dst = h;
}

// ---------------------------------------------------------------- K0: weight prep
__global__ void k0_prep(const float* __restrict__ W1, const float* __restrict__ W3,
                        unsigned short* __restrict__ W1bT, unsigned short* __restrict__ W3bT) {
  int i = blockIdx.x * 256 + threadIdx.x;
  if (i < 16384) {
    int n = i >> 7, k = i & 127;
    W1bT[i] = f2bf(W1[k * 128 + n]);
  } else if (i < 16384 + 24576) {
    int j = i - 16384;
    int n = j / 192, k = j % 192;
    W3bT[j] = f2bf(W3[k * 128 + n]);
  }
}

// ---------------------------------------------------------------- sort: histogram
__global__ void k_hist(const int* __restrict__ eidx, int* __restrict__ hist) {
  int e = blockIdx.x * 256 + threadIdx.x;
  if (e < NE) atomicAdd(&hist[eidx[NE + e]], 1);
}

// ---------------------------------------------------------------- sort: scan (1 block)
__global__ void k_scan(int* __restrict__ hist, float* __restrict__ cntF) {
  __shared__ int ssum[1024];
  const int t = threadIdx.x;
  const int base = t * 98;                       // 1024*98 = 100352 >= NN
  const int cl = (base >= NN) ? 0 : ((NN - base < 98) ? (NN - base) : 98);
  int s = 0;
  for (int i = 0; i < cl; i++) s += hist[base + i];
  ssum[t] = s;
  __syncthreads();
  for (int d = 1; d < 1024; d <<= 1) {
    int v = (t >= d) ? ssum[t - d] : 0;
    __syncthreads();
    ssum[t] += v;
    __syncthreads();
  }
  int run = (t == 0) ? 0 : ssum[t - 1];
  for (int i = 0; i < cl; i++) {
    int hv = hist[base + i];
    hist[base + i] = run;                        // exclusive offsets, in place
    cntF[base + i] = (float)hv;
    run += hv;
  }
}

// ---------------------------------------------------------------- sort: scatter
__global__ void k_scatter(const int* __restrict__ eidx, int* __restrict__ off,
                          int2* __restrict__ pairS) {
  int e = blockIdx.x * 256 + threadIdx.x;
  if (e < NE) {
    int c = eidx[NE + e];
    int p = atomicAdd(&off[c], 1);
    pairS[p] = make_int2(c, e);
  }
}

// ---------------------------------------------------------------- K1: edge pass (sorted)
// 512 threads / 8 waves, each owns a 32x64 quadrant (acc[2][4]).
// Occupancy model (validated on r0/r1/r2 counters): pool = 512 regs/SIMD,
// MFMA acc in AGPRs is allocated in a 64-reg granule. r2's (512,2) gave
// 72 VGPR + 64-pad AGPR = 136 -> 3 waves/SIMD -> only 1 block/CU (23% occ).
// Fix: amdgpu_waves_per_eu(4) -> allocator must fit 4 waves/EU (<=128 total),
// which forces the 32-reg acc into arch VGPRs (total ~104) -> 2 blocks/CU
// = 16 waves/CU. LDS 70,656 x 2 = 141 KB fits.
__global__ __attribute__((amdgpu_flat_work_group_size(512, 512)))
__attribute__((amdgpu_waves_per_eu(4))) void k1_edge(
    const float* __restrict__ x, const int* __restrict__ eidx,
    const float* __restrict__ ea, const unsigned short* __restrict__ W1bT,
    const float* __restrict__ b1, const int2* __restrict__ pairS,
    float* __restrict__ S, float* __restrict__ stat1) {
  __shared__ __align__(16) char HAt[67584];      // H f32[128][132]; At ushort[128][136] aliases
  __shared__ int rIdxS[128];
  __shared__ int eIdxS[128];
  __shared__ int colT[132];    // colT[i+1] = dest node of local row i; [0]/[129] halos
  __shared__ float sred[256];
  unsigned short (*At)[136] = (unsigned short (*)[136])HAt;
  float (*H)[132] = (float (*)[132])HAt;

  const int tid = threadIdx.x;
  const int wave = tid >> 6, lane = tid & 63;
  const int l15 = lane & 15, quad = lane >> 4;
  const int rowbase = (wave >> 1) * 32;          // 4 row-groups of 32
  const int colbase = (wave & 1) * 64;           // 2 col-halves

  float b1j[4];
#pragma unroll
  for (int ct = 0; ct < 4; ct++) b1j[ct] = b1[colbase + ct * 16 + l15];

  float lsum[4] = {0, 0, 0, 0}, lsq[4] = {0, 0, 0, 0};

  for (int tile = blockIdx.x; tile < NTILE_E; tile += gridDim.x) {
    const int eb = tile * 128;
    __syncthreads();   // previous iteration's walk readers done (H region free)
    if (tid < 128) {
      int2 pr = pairS[eb + tid];
      eIdxS[tid] = pr.y;
      rIdxS[tid] = eidx[pr.y];
      colT[tid + 1] = pr.x;
    } else if (tid == 128) {
      colT[0] = (eb > 0) ? pairS[eb - 1].x : -1;
    } else if (tid == 129) {
      colT[129] = (eb + 128 < NE) ? pairS[eb + 128].x : -1;
    }
    __syncthreads();
#pragma unroll
    for (int i = 0; i < 4; i++) {
      int idx = tid + i * 512; int e = idx >> 4, c = idx & 15;
      float4 v = ((const float4*)x)[(size_t)rIdxS[e] * 16 + c];
      pack4(v, &At[e][c * 4]);
    }
#pragma unroll
    for (int i = 0; i < 4; i++) {
      int idx = tid + i * 512; int e = idx >> 4, c = idx & 15;
      float4 v = ((const float4*)ea)[(size_t)eIdxS[e] * 16 + c];
      pack4(v, &At[e][64 + c * 4]);
    }
    __syncthreads();

    f32x4 acc[2][4];
#pragma unroll
    for (int rt = 0; rt < 2; rt++)
#pragma unroll
      for (int ct = 0; ct < 4; ct++) acc[rt][ct] = (f32x4){0.f, 0.f, 0.f, 0.f};

    // laundered base: compiler cannot prove loads below are tile-invariant,
    // so bf[][] stays a 32-reg working set instead of a 64-reg resident array
    unsigned woff = 0;
    asm volatile("" : "+v"(woff));
    const unsigned short* W1v = W1bT + woff;

#pragma unroll
    for (int half = 0; half < 2; half++) {
      s16x8 bf[4][2];
#pragma unroll
      for (int ct = 0; ct < 4; ct++)
#pragma unroll
        for (int j = 0; j < 2; j++)
          bf[ct][j] = *(const s16x8*)(W1v + (colbase + ct * 16 + l15) * 128 + (half * 2 + j) * 32 + quad * 8);
#pragma unroll
      for (int j = 0; j < 2; j++) {
        s16x8 af[2];
#pragma unroll
        for (int rt = 0; rt < 2; rt++)
          af[rt] = *(const s16x8*)&At[rowbase + rt * 16 + l15][(half * 2 + j) * 32 + quad * 8];
#pragma unroll
        for (int rt = 0; rt < 2; rt++)
#pragma unroll
          for (int ct = 0; ct < 4; ct++)
            acc[rt][ct] = __builtin_amdgcn_mfma_f32_16x16x32_bf16(af[rt], bf[ct][j], acc[rt][ct], 0, 0, 0);
      }
    }

    __syncthreads();   // all MFMA reads of At done; safe to overwrite (H aliases At)
    // write post-leaky h1 (f32) to full-width H
#pragma unroll
    for (int rt = 0; rt < 2; rt++)
#pragma unroll
      for (int r = 0; r < 4; r++) {
        const int er = rowbase + rt * 16 + quad * 4 + r;
#pragma unroll
        for (int ct = 0; ct < 4; ct++) {
          float v = acc[rt][ct][r] + b1j[ct];
          v = v > 0.0f ? v : 0.01f * v;
          lsum[ct] += v; lsq[ct] += v * v;
          H[er][colbase + ct * 16 + l15] = v;
        }
      }
    __syncthreads();

    // segmented flush: thread -> (col = tid&127, rows [r0, r0+32)); single pass
    {
      const int col = tid & 127;
      const int r0 = (tid >> 7) * 32;
      float runsum = H[r0][col];
      int runstart = r0;
      int curnode = colT[r0 + 1];
      for (int r = r0 + 1; r < r0 + 32; ++r) {
        int nd = colT[r + 1];
        float v = H[r][col];
        if (nd == curnode) { runsum += v; }
        else {
          float* p = S + (size_t)curnode * 128 + col;
          if (colT[runstart] != curnode) *p = runsum;   // run complete (end change observed)
          else atomicAdd(p, runsum);
          curnode = nd; runsum = v; runstart = r;
        }
      }
      float* p = S + (size_t)curnode * 128 + col;
      if (colT[runstart] != curnode && colT[r0 + 33] != curnode) *p = runsum;
      else atomicAdd(p, runsum);
    }
  }

  if (tid < 256) sred[tid] = 0.0f;
  __syncthreads();
#pragma unroll
  for (int ct = 0; ct < 4; ct++) {
    float s = lsum[ct], q = lsq[ct];
    s += __shfl_down(s, 32); q += __shfl_down(q, 32);
    s += __shfl_down(s, 16); q += __shfl_down(q, 16);
    if (lane < 16) {
      atomicAdd(&sred[colbase + ct * 16 + l15], s);
      atomicAdd(&sred[128 + colbase + ct * 16 + l15], q);
    }
  }
  __syncthreads();
  if (tid < 256) atomicAdd(&stat1[tid], sred[tid]);
}

// ---------------------------------------------------------------- K2: fold BN1 into W2
__global__ void k2_fold1(const float* __restrict__ stat1, const float* __restrict__ g1,
                         const float* __restrict__ be1, const float* __restrict__ W2,
                         const float* __restrict__ b2,
                         unsigned short* __restrict__ W2pT, float* __restrict__ v128) {
  __shared__ float s1s[128], t1s[128];
  __shared__ float red[256];
  const int tid = threadIdx.x;
  if (tid < 128) {
    float mean = stat1[tid] * (1.0f / NE);
    float var = stat1[128 + tid] * (1.0f / NE) - mean * mean;
    float rstd = rsqrtf(var + 1e-5f);
    float s = g1[tid] * rstd;
    s1s[tid] = s; t1s[tid] = be1[tid] - mean * s;
  }
  __syncthreads();
  const int b = blockIdx.x;
  if (b < 16) {
#pragma unroll
    for (int j = 0; j < 4; j++) {
      int i = b * 1024 + j * 256 + tid;          // i indexes W2 [k][n] row-major
      int k = i >> 7, n = i & 127;
      W2pT[n * 128 + k] = f2bf(s1s[k] * W2[i]);
    }
  } else {
    int j = tid & 127, hh = tid >> 7;
    float p = 0.f;
    for (int k = hh * 64; k < hh * 64 + 64; k++) p += t1s[k] * W2[k * 128 + j];
    red[tid] = p;
    __syncthreads();
    if (tid < 128) v128[tid] = red[tid] + red[tid + 128] + b2[tid];
  }
}

// ---------------------------------------------------------------- K3: node pass
// Unified LDS buffer [128][200]: x in cols 0..63, S (then t1) in cols 64..191.
// launch_bounds back to (256,2): the (256,3) variant implies a tighter
// allocator cap under the CUDA-style min-blocks translation (spill risk).
__global__ __launch_bounds__(256, 2) void k3_node(
    const float* __restrict__ x, const float* __restrict__ S, const float* __restrict__ cnt,
    const unsigned short* __restrict__ W2pT, const float* __restrict__ v128,
    const unsigned short* __restrict__ W3bT, const float* __restrict__ b3,
    unsigned short* __restrict__ tOut, float* __restrict__ stat2) {
  __shared__ __align__(16) unsigned short Abuf[128][200];
  __shared__ float cbuf[128];
  __shared__ float sred[256];

  const int tid = threadIdx.x;
  const int wave = tid >> 6, lane = tid & 63;
  const int l15 = lane & 15, quad = lane >> 4;
  const int rowbase = (wave >> 1) * 64;
  const int colbase = (wave & 1) * 64;

  float vj[4], b3j[4];
#pragma unroll
  for (int ct = 0; ct < 4; ct++) {
    int jc = colbase + ct * 16 + l15;
    vj[ct] = v128[jc]; b3j[ct] = b3[jc];
  }
  float lsum[4] = {0, 0, 0, 0}, lsq[4] = {0, 0, 0, 0};

  for (int t = blockIdx.x; t < NTILE_N; t += gridDim.x) {
    const int nb = t * 128;
    __syncthreads();
#pragma unroll
    for (int i = 0; i < 8; i++) {               // x -> cols 0..63
      int idx = tid + i * 256; int e = idx >> 4, c = idx & 15;
      int node = nb + e;
      float4 v = {0.f, 0.f, 0.f, 0.f};
      if (node < NN) v = ((const float4*)x)[(size_t)node * 16 + c];
      pack4(v, &Abuf[e][c * 4]);
    }
#pragma unroll
    for (int i = 0; i < 16; i++) {              // S -> cols 64..191
      int idx = tid + i * 256; int e = idx >> 5, c = idx & 31;
      int node = nb + e;
      float4 v = {0.f, 0.f, 0.f, 0.f};
      if (node < NN) v = ((const float4*)S)[(size_t)node * 32 + c];
      pack4(v, &Abuf[e][64 + c * 4]);
    }
    if (tid < 128) cbuf[tid] = (nb + tid < NN) ? cnt[nb + tid] : 0.0f;
    __syncthreads();

    f32x4 acc[4][4];
#pragma unroll
    for (int rt = 0; rt < 4; rt++)
#pragma unroll
      for (int ct = 0; ct < 4; ct++) acc[rt][ct] = (f32x4){0.f, 0.f, 0.f, 0.f};
#pragma unroll
    for (int ks = 0; ks < 4; ks++) {
      s16x8 af[4];
#pragma unroll
      for (int rt = 0; rt < 4; rt++)
        af[rt] = *(const s16x8*)&Abuf[rowbase + rt * 16 + l15][64 + ks * 32 + quad * 8];
      s16x8 bfr[4];
#pragma unroll
      for (int ct = 0; ct < 4; ct++)
        bfr[ct] = *(const s16x8*)(W2pT + (colbase + ct * 16 + l15) * 128 + ks * 32 + quad * 8);
#pragma unroll
      for (int rt = 0; rt < 4; rt++)
#pragma unroll
        for (int ct = 0; ct < 4; ct++)
          acc[rt][ct] = __builtin_amdgcn_mfma_f32_16x16x32_bf16(af[rt], bfr[ct], acc[rt][ct], 0, 0, 0);
    }
    __syncthreads();
#pragma unroll
    for (int rt = 0; rt < 4; rt++)
#pragma unroll
      for (int r = 0; r < 4; r++) {
        int er = rowbase + rt * 16 + quad * 4 + r;
#pragma unroll
        for (int ct = 0; ct < 4; ct++) {
          float val = acc[rt][ct][r] + cbuf[er] * vj[ct];
          Abuf[er][64 + colbase + ct * 16 + l15] = f2bf(val);   // t1 overwrites S region
        }
      }
    __syncthreads();

    f32x4 acc2[4][4];
#pragma unroll
    for (int rt = 0; rt < 4; rt++)
#pragma unroll
      for (int ct = 0; ct < 4; ct++) acc2[rt][ct] = (f32x4){0.f, 0.f, 0.f, 0.f};
#pragma unroll
    for (int ks = 0; ks < 6; ks++) {            // K=192: cols 0..191 = [x | t1]
      s16x8 af[4];
#pragma unroll
      for (int rt = 0; rt < 4; rt++)
        af[rt] = *(const s16x8*)&Abuf[rowbase + rt * 16 + l15][ks * 32 + quad * 8];
      s16x8 bfr[4];
#pragma unroll
      for (int ct = 0; ct < 4; ct++)
        bfr[ct] = *(const s16x8*)(W3bT + (size_t)(colbase + ct * 16 + l15) * 192 + ks * 32 + quad * 8);
#pragma unroll
      for (int rt = 0; rt < 4; rt++)
#pragma unroll
        for (int ct = 0; ct < 4; ct++)
          acc2[rt][ct] = __builtin_amdgcn_mfma_f32_16x16x32_bf16(af[rt], bfr[ct], acc2[rt][ct], 0, 0, 0);
    }

#pragma unroll
    for (int rt = 0; rt < 4; rt++)
#pragma unroll
      for (int r = 0; r < 4; r++) {
        int er = rowbase + rt * 16 + quad * 4 + r;
        int node = nb + er;
        if (node < NN) {
#pragma unroll
          for (int ct = 0; ct < 4; ct++) {
            float val = acc2[rt][ct][r] + b3j[ct];
            val = val > 0.0f ? val : 0.01f * val;
            lsum[ct] += val; lsq[ct] += val * val;
            tOut[(size_t)node * 128 + colbase + ct * 16 + l15] = f2bf(val);
          }
        }
      }
  }

  sred[tid] = 0.0f;
  __syncthreads();
#pragma unroll
  for (int ct = 0; ct < 4; ct++) {
    float s = lsum[ct], q = lsq[ct];
    s += __shfl_down(s, 32); q += __shfl_down(q, 32);
    s += __shfl_down(s, 16); q += __shfl_down(q, 16);
    if (lane < 16) {
      atomicAdd(&sred[colbase + ct * 16 + l15], s);
      atomicAdd(&sred[128 + colbase + ct * 16 + l15], q);
    }
  }
  __syncthreads();
  atomicAdd(&stat2[tid], sred[tid]);
}

// ---------------------------------------------------------------- K5: fold BN2 into W4
__global__ void k5_fold2(const float* __restrict__ stat2, const float* __restrict__ g2,
                         const float* __restrict__ be2, const float* __restrict__ W4,
                         const float* __restrict__ b4,
                         unsigned short* __restrict__ W4fT, float* __restrict__ b4f) {
  __shared__ float s2s[128], t2s[128];
  __shared__ float red[256];
  const int tid = threadIdx.x;
  if (tid < 128) {
    float mean = stat2[tid] * (1.0f / NN);
    float var = stat2[128 + tid] * (1.0f / NN) - mean * mean;
    float rstd = rsqrtf(var + 1e-5f);
    float s = g2[tid] * rstd;
    s2s[tid] = s; t2s[tid] = be2[tid] - mean * s;
  }
  __syncthreads();
  const int b = blockIdx.x;
  if (b < 8) {
#pragma unroll
    for (int j = 0; j < 4; j++) {
      int i = b * 1024 + j * 256 + tid;          // i indexes W4 [k][n] row-major, n<64
      int k = i >> 6, n = i & 63;
      W4fT[n * 128 + k] = f2bf(s2s[k] * W4[i]);
    }
  } else {
    int j = tid & 63, part = tid >> 6;
    float p = 0.f;
    for (int k = part * 32; k < part * 32 + 32; k++) p += t2s[k] * W4[k * 64 + j];
    red[tid] = p;
    __syncthreads();
    if (tid < 64) b4f[tid] = red[tid] + red[tid + 64] + red[tid + 128] + red[tid + 192] + b4[tid];
  }
}

// ---------------------------------------------------------------- K6: out = t @ W4f + b4f
__global__ __launch_bounds__(256, 2) void k6_out(
    const unsigned short* __restrict__ tIn, const unsigned short* __restrict__ W4fT,
    const float* __restrict__ b4f, float* __restrict__ out) {
  __shared__ unsigned short Abuf[128][136];
  const int tid = threadIdx.x;
  const int wave = tid >> 6, lane = tid & 63;
  const int l15 = lane & 15, quad = lane >> 4;
  const int rowbase = (wave >> 1) * 64;
  const int colbase = (wave & 1) * 32;

  s16x8 bfrag[2][4];
#pragma unroll
  for (int ct = 0; ct < 2; ct++)
#pragma unroll
    for (int ks = 0; ks < 4; ks++)
      bfrag[ct][ks] = *(const s16x8*)(W4fT + (colbase + ct * 16 + l15) * 128 + ks * 32 + quad * 8);
  float bj[2];
#pragma unroll
  for (int ct = 0; ct < 2; ct++) bj[ct] = b4f[colbase + ct * 16 + l15];

  for (int t = blockIdx.x; t < NTILE_N; t += gridDim.x) {
    const int nb = t * 128;
    __syncthreads();
#pragma unroll
    for (int i = 0; i < 8; i++) {
      int idx = tid + i * 256; int e = idx >> 4, c = idx & 15;
      int node = nb + e;
      s16x8 v = {0, 0, 0, 0, 0, 0, 0, 0};
      if (node < NN) v = *(const s16x8*)(tIn + (size_t)node * 128 + c * 8);
      *(s16x8*)&Abuf[e][c * 8] = v;
    }
    __syncthreads();

    f32x4 acc[4][2];
#pragma unroll
    for (int rt = 0; rt < 4; rt++)
#pragma unroll
      for (int ct = 0; ct < 2; ct++) acc[rt][ct] = (f32x4){0.f, 0.f, 0.f, 0.f};
#pragma unroll
    for (int ks = 0; ks < 4; ks++) {
      s16x8 af[4];
#pragma unroll
      for (int rt = 0; rt < 4; rt++)
        af[rt] = *(const s16x8*)&Abuf[rowbase + rt * 16 + l15][ks * 32 + quad * 8];
#pragma unroll
      for (int rt = 0; rt < 4; rt++)
#pragma unroll
        for (int ct = 0; ct < 2; ct++)
          acc[rt][ct] = __builtin_amdgcn_mfma_f32_16x16x32_bf16(af[rt], bfrag[ct][ks], acc[rt][ct], 0, 0, 0);
    }
#pragma unroll
    for (int rt = 0; rt < 4; rt++)
#pragma unroll
      for (int r = 0; r < 4; r++) {
        int er = rowbase + rt * 16 + quad * 4 + r;
        int node = nb + er;
        if (node < NN) {
#pragma unroll
          for (int ct = 0; ct < 2; ct++)
            out[(size_t)node * 64 + colbase + ct * 16 + l15] = acc[rt][ct][r] + bj[ct];
        }
      }
  }
}

// ---------------------------------------------------------------- launch
extern "C" void kernel_launch(void* const* d_in, const int* in_sizes, int n_in,
                              void* d_out, int out_size, void* d_ws, size_t ws_size,
                              hipStream_t stream) {
  (void)in_sizes; (void)n_in; (void)out_size; (void)ws_size;
  const float* x   = (const float*)d_in[0];
  const int*   ei  = (const int*)d_in[1];
  const float* ea  = (const float*)d_in[2];
  const float* W1  = (const float*)d_in[5];
  const float* b1  = (const float*)d_in[6];
  const float* g1  = (const float*)d_in[7];
  const float* be1 = (const float*)d_in[8];
  const float* W2  = (const float*)d_in[9];
  const float* b2  = (const float*)d_in[10];
  const float* W3  = (const float*)d_in[11];
  const float* b3  = (const float*)d_in[12];
  const float* g2  = (const float*)d_in[13];
  const float* be2 = (const float*)d_in[14];
  const float* W4  = (const float*)d_in[15];
  const float* b4  = (const float*)d_in[16];
  float* out = (float*)d_out;

  char* w = (char*)d_ws;
  float* S     = (float*)(w);                              // 51,200,000
  float* stat1 = (float*)(w + 51200000);                   //      1,024
  float* stat2 = (float*)(w + 51201024);                   //      1,024
  int*   hist  = (int*)  (w + 51202048);                   //    400,384  (also off[])
  float* cntF  = (float*)(w + 51602432);                   //    400,384
  unsigned short* W1bT = (unsigned short*)(w + 52002816);  //     32,768
  unsigned short* W3bT = (unsigned short*)(w + 52035584);  //     49,152
  unsigned short* W2pT = (unsigned short*)(w + 52084736);  //     32,768
  float* v128  = (float*)(w + 52117504);                   //        512
  unsigned short* W4fT = (unsigned short*)(w + 52118016);  //     16,384
  float* b4f   = (float*)(w + 52134400);                   //        256
  unsigned short* tOut = (unsigned short*)(w + 52134656);  // 25,600,000
  // pairS (12.8 MB, int2 {col,e}) aliases tOut's space — lifetimes disjoint (sort+k1 vs k3+k6)
  int2* pairS = (int2*)(w + 52134656);                     // 12,800,000
  // total ws use: 77,734,656 B

  hipMemsetAsync(d_ws, 0, 51602432, stream);   // zero S + stat1 + stat2 + hist

  k0_prep<<<160, 256, 0, stream>>>(W1, W3, W1bT, W3bT);
  k_hist<<<6250, 256, 0, stream>>>(ei, hist);
  k_scan<<<1, 1024, 0, stream>>>(hist, cntF);
  k_scatter<<<6250, 256, 0, stream>>>(ei, hist, pairS);
  k1_edge<<<512, 512, 0, stream>>>(x, ei, ea, W1bT, b1, pairS, S, stat1);
  k2_fold1<<<17, 256, 0, stream>>>(stat1, g1, be1, W2, b2, W2pT, v128);
  k3_node<<<512, 256, 0, stream>>>(x, S, cntF, W2pT, v128, W3bT, b3, tOut, stat2);
  k5_fold2<<<9, 256, 0, stream>>>(stat2, g2, be2, W4, b4, W4fT, b4f);
  k6_out<<<512, 256, 0, stream>>>(tOut, W4fT, b4f, out);
}

// Round 4
// 1209.084 us; speedup vs baseline: 1.2265x; 1.0907x over previous
//
#include <hip/hip_runtime.h>

#define NN 100000
#define NE 1600000
#define NTILE_E (NE / 128)      // 12500, exact
#define NTILE_N 782             // ceil(100000/128)

typedef __attribute__((ext_vector_type(4))) float f32x4;
typedef __attribute__((ext_vector_type(8))) short s16x8;

__device__ __forceinline__ unsigned short f2bf(float f) {
  unsigned u = __builtin_bit_cast(unsigned, f);
  u = (u + 0x7FFFu + ((u >> 16) & 1u)) >> 16;
  return (unsigned short)u;
}
__device__ __forceinline__ void pack4(float4 v, unsigned short* dst) {
  ushort4 h;
  h.x = f2bf(v.x); h.y = f2bf(v.y); h.z = f2bf(v.z); h.w = f2bf(v.w);
  *(ushort4*)dst = h;
}

// ---------------------------------------------------------------- K0: weight prep
__global__ void k0_prep(const float* __restrict__ W1, const float* __restrict__ W3,
                        unsigned short* __restrict__ W1bT, unsigned short* __restrict__ W3bT) {
  int i = blockIdx.x * 256 + threadIdx.x;
  if (i < 16384) {
    int n = i >> 7, k = i & 127;
    W1bT[i] = f2bf(W1[k * 128 + n]);
  } else if (i < 16384 + 24576) {
    int j = i - 16384;
    int n = j / 192, k = j % 192;
    W3bT[j] = f2bf(W3[k * 128 + n]);
  }
}

// ---------------------------------------------------------------- sort: histogram
__global__ void k_hist(const int* __restrict__ eidx, int* __restrict__ hist) {
  int e = blockIdx.x * 256 + threadIdx.x;
  if (e < NE) atomicAdd(&hist[eidx[NE + e]], 1);
}

// ---------------------------------------------------------------- sort: scan (1 block)
__global__ void k_scan(int* __restrict__ hist, float* __restrict__ cntF) {
  __shared__ int ssum[1024];
  const int t = threadIdx.x;
  const int base = t * 98;                       // 1024*98 = 100352 >= NN
  const int cl = (base >= NN) ? 0 : ((NN - base < 98) ? (NN - base) : 98);
  int s = 0;
  for (int i = 0; i < cl; i++) s += hist[base + i];
  ssum[t] = s;
  __syncthreads();
  for (int d = 1; d < 1024; d <<= 1) {
    int v = (t >= d) ? ssum[t - d] : 0;
    __syncthreads();
    ssum[t] += v;
    __syncthreads();
  }
  int run = (t == 0) ? 0 : ssum[t - 1];
  for (int i = 0; i < cl; i++) {
    int hv = hist[base + i];
    hist[base + i] = run;                        // exclusive offsets, in place
    cntF[base + i] = (float)hv;
    run += hv;
  }
}

// ---------------------------------------------------------------- sort: scatter
__global__ void k_scatter(const int* __restrict__ eidx, int* __restrict__ off,
                          int2* __restrict__ pairS) {
  int e = blockIdx.x * 256 + threadIdx.x;
  if (e < NE) {
    int c = eidx[NE + e];
    int p = atomicAdd(&off[c], 1);
    pairS[p] = make_int2(c, e);
  }
}

// ---------------------------------------------------------------- K1: edge pass (sorted)
// 512 threads / 8 waves. Wave tile = 64 rows x 32 cols: acc[4][2] (32 AGPR) +
// RESIDENT bfrag[2][4] (32 VGPR, wave's 32 cols x K=128). Total ~102 regs/wave
// <= 128 -> 4 waves/SIMD (16 waves/CU) with NO spill (round-1 failure) and NO
// per-tile weight reload (round-3 failure: 128 KB/tile/block L1-thrash).
// Index arrays double-buffered: next tile's pairS+eidx dependent-gather chain
// issues during current tile's staging, hiding it under MFMA+walk.
__global__ __attribute__((amdgpu_flat_work_group_size(512, 512)))
__attribute__((amdgpu_waves_per_eu(4))) void k1_edge(
    const float* __restrict__ x, const int* __restrict__ eidx,
    const float* __restrict__ ea, const unsigned short* __restrict__ W1bT,
    const float* __restrict__ b1, const int2* __restrict__ pairS,
    float* __restrict__ S, float* __restrict__ stat1) {
  __shared__ __align__(16) char HAt[67584];      // H f32[128][132]; At ushort[128][136] aliases
  __shared__ int rIdx2[2][128];
  __shared__ int eIdx2[2][128];
  __shared__ int colT2[2][132];   // colT[i+1] = dest node of local row i; [0]/[129] halos
  __shared__ float sred[256];
  unsigned short (*At)[136] = (unsigned short (*)[136])HAt;
  float (*H)[132] = (float (*)[132])HAt;

  const int tid = threadIdx.x;
  const int wave = tid >> 6, lane = tid & 63;
  const int l15 = lane & 15, quad = lane >> 4;
  const int rowbase = (wave >> 2) * 64;          // 2 row-groups of 64
  const int colbase = (wave & 3) * 32;           // 4 col-groups of 32

  // resident B fragments: wave's 32 output cols, full K=128 (32 VGPRs)
  s16x8 bfrag[2][4];
#pragma unroll
  for (int ct = 0; ct < 2; ct++)
#pragma unroll
    for (int ks = 0; ks < 4; ks++)
      bfrag[ct][ks] = *(const s16x8*)(W1bT + (colbase + ct * 16 + l15) * 128 + ks * 32 + quad * 8);

  float b1j[2];
#pragma unroll
  for (int ct = 0; ct < 2; ct++) b1j[ct] = b1[colbase + ct * 16 + l15];

  float lsum[2] = {0, 0}, lsq[2] = {0, 0};

  // prologue: load indices for first tile into buffer 0
  {
    const int eb = blockIdx.x * 128;
    if (tid < 128) {
      int2 pr = pairS[eb + tid];
      eIdx2[0][tid] = pr.y;
      rIdx2[0][tid] = eidx[pr.y];
      colT2[0][tid + 1] = pr.x;
    } else if (tid == 128) {
      colT2[0][0] = (eb > 0) ? pairS[eb - 1].x : -1;
    } else if (tid == 129) {
      colT2[0][129] = (eb + 128 < NE) ? pairS[eb + 128].x : -1;
    }
  }

  int p = 0;
  for (int tile = blockIdx.x; tile < NTILE_E; tile += gridDim.x) {
    __syncthreads();   // (A) prev walk done; idx[p] (prologue or prev prefetch) visible
#pragma unroll
    for (int i = 0; i < 4; i++) {
      int idx = tid + i * 512; int e = idx >> 4, c = idx & 15;
      float4 v = ((const float4*)x)[(size_t)rIdx2[p][e] * 16 + c];
      pack4(v, &At[e][c * 4]);
    }
#pragma unroll
    for (int i = 0; i < 4; i++) {
      int idx = tid + i * 512; int e = idx >> 4, c = idx & 15;
      float4 v = ((const float4*)ea)[(size_t)eIdx2[p][e] * 16 + c];
      pack4(v, &At[e][64 + c * 4]);
    }
    // prefetch next tile's indices into buf p^1 (overlaps with staging + MFMA)
    {
      const int ntile = tile + gridDim.x;
      if (ntile < NTILE_E) {
        const int eb2 = ntile * 128;
        if (tid < 128) {
          int2 pr = pairS[eb2 + tid];
          eIdx2[p ^ 1][tid] = pr.y;
          rIdx2[p ^ 1][tid] = eidx[pr.y];
          colT2[p ^ 1][tid + 1] = pr.x;
        } else if (tid == 128) {
          colT2[p ^ 1][0] = pairS[eb2 - 1].x;
        } else if (tid == 129) {
          colT2[p ^ 1][129] = (eb2 + 128 < NE) ? pairS[eb2 + 128].x : -1;
        }
      }
    }
    __syncthreads();   // (B) staging + prefetch writes visible

    f32x4 acc[4][2];
#pragma unroll
    for (int rt = 0; rt < 4; rt++)
#pragma unroll
      for (int ct = 0; ct < 2; ct++) acc[rt][ct] = (f32x4){0.f, 0.f, 0.f, 0.f};

#pragma unroll
    for (int ks = 0; ks < 4; ks++) {
      s16x8 af[4];
#pragma unroll
      for (int rt = 0; rt < 4; rt++)
        af[rt] = *(const s16x8*)&At[rowbase + rt * 16 + l15][ks * 32 + quad * 8];
#pragma unroll
      for (int rt = 0; rt < 4; rt++)
#pragma unroll
        for (int ct = 0; ct < 2; ct++)
          acc[rt][ct] = __builtin_amdgcn_mfma_f32_16x16x32_bf16(af[rt], bfrag[ct][ks], acc[rt][ct], 0, 0, 0);
    }

    __syncthreads();   // (C) all MFMA reads of At done; safe to overwrite (H aliases At)
#pragma unroll
    for (int rt = 0; rt < 4; rt++)
#pragma unroll
      for (int r = 0; r < 4; r++) {
        const int er = rowbase + rt * 16 + quad * 4 + r;
#pragma unroll
        for (int ct = 0; ct < 2; ct++) {
          float v = acc[rt][ct][r] + b1j[ct];
          v = v > 0.0f ? v : 0.01f * v;
          lsum[ct] += v; lsq[ct] += v * v;
          H[er][colbase + ct * 16 + l15] = v;
        }
      }
    __syncthreads();   // (D)

    // segmented flush: thread -> (col = tid&127, rows [r0, r0+32)); single pass
    {
      const int col = tid & 127;
      const int r0 = (tid >> 7) * 32;
      float runsum = H[r0][col];
      int runstart = r0;
      int curnode = colT2[p][r0 + 1];
      for (int r = r0 + 1; r < r0 + 32; ++r) {
        int nd = colT2[p][r + 1];
        float v = H[r][col];
        if (nd == curnode) { runsum += v; }
        else {
          float* pp = S + (size_t)curnode * 128 + col;
          if (colT2[p][runstart] != curnode) *pp = runsum;   // run complete
          else atomicAdd(pp, runsum);
          curnode = nd; runsum = v; runstart = r;
        }
      }
      float* pp = S + (size_t)curnode * 128 + col;
      if (colT2[p][runstart] != curnode && colT2[p][r0 + 33] != curnode) *pp = runsum;
      else atomicAdd(pp, runsum);
    }
    p ^= 1;
  }

  if (tid < 256) sred[tid] = 0.0f;
  __syncthreads();
#pragma unroll
  for (int ct = 0; ct < 2; ct++) {
    float s = lsum[ct], q = lsq[ct];
    s += __shfl_down(s, 32); q += __shfl_down(q, 32);
    s += __shfl_down(s, 16); q += __shfl_down(q, 16);
    if (lane < 16) {
      atomicAdd(&sred[colbase + ct * 16 + l15], s);
      atomicAdd(&sred[128 + colbase + ct * 16 + l15], q);
    }
  }
  __syncthreads();
  if (tid < 256) atomicAdd(&stat1[tid], sred[tid]);
}

// ---------------------------------------------------------------- K2: fold BN1 into W2
__global__ void k2_fold1(const float* __restrict__ stat1, const float* __restrict__ g1,
                         const float* __restrict__ be1, const float* __restrict__ W2,
                         const float* __restrict__ b2,
                         unsigned short* __restrict__ W2pT, float* __restrict__ v128) {
  __shared__ float s1s[128], t1s[128];
  __shared__ float red[256];
  const int tid = threadIdx.x;
  if (tid < 128) {
    float mean = stat1[tid] * (1.0f / NE);
    float var = stat1[128 + tid] * (1.0f / NE) - mean * mean;
    float rstd = rsqrtf(var + 1e-5f);
    float s = g1[tid] * rstd;
    s1s[tid] = s; t1s[tid] = be1[tid] - mean * s;
  }
  __syncthreads();
  const int b = blockIdx.x;
  if (b < 16) {
#pragma unroll
    for (int j = 0; j < 4; j++) {
      int i = b * 1024 + j * 256 + tid;          // i indexes W2 [k][n] row-major
      int k = i >> 7, n = i & 127;
      W2pT[n * 128 + k] = f2bf(s1s[k] * W2[i]);
    }
  } else {
    int j = tid & 127, hh = tid >> 7;
    float p = 0.f;
    for (int k = hh * 64; k < hh * 64 + 64; k++) p += t1s[k] * W2[k * 128 + j];
    red[tid] = p;
    __syncthreads();
    if (tid < 128) v128[tid] = red[tid] + red[tid + 128] + b2[tid];
  }
}

// ---------------------------------------------------------------- K3: node pass (round-0 proven)
__global__ __launch_bounds__(256, 2) void k3_node(
    const float* __restrict__ x, const float* __restrict__ S, const float* __restrict__ cnt,
    const unsigned short* __restrict__ W2pT, const float* __restrict__ v128,
    const unsigned short* __restrict__ W3bT, const float* __restrict__ b3,
    unsigned short* __restrict__ tOut, float* __restrict__ stat2) {
  __shared__ unsigned short Abuf[128][136];
  __shared__ unsigned short Xbuf[128][72];
  __shared__ float cbuf[128];
  __shared__ float sred[256];

  const int tid = threadIdx.x;
  const int wave = tid >> 6, lane = tid & 63;
  const int l15 = lane & 15, quad = lane >> 4;
  const int rowbase = (wave >> 1) * 64;
  const int colbase = (wave & 1) * 64;

  float vj[4], b3j[4];
#pragma unroll
  for (int ct = 0; ct < 4; ct++) {
    int jc = colbase + ct * 16 + l15;
    vj[ct] = v128[jc]; b3j[ct] = b3[jc];
  }
  float lsum[4] = {0, 0, 0, 0}, lsq[4] = {0, 0, 0, 0};

  for (int t = blockIdx.x; t < NTILE_N; t += gridDim.x) {
    const int nb = t * 128;
    __syncthreads();
#pragma unroll
    for (int i = 0; i < 16; i++) {
      int idx = tid + i * 256; int e = idx >> 5, c = idx & 31;
      int node = nb + e;
      float4 v = {0.f, 0.f, 0.f, 0.f};
      if (node < NN) v = ((const float4*)S)[(size_t)node * 32 + c];
      pack4(v, &Abuf[e][c * 4]);
    }
#pragma unroll
    for (int i = 0; i < 8; i++) {
      int idx = tid + i * 256; int e = idx >> 4, c = idx & 15;
      int node = nb + e;
      float4 v = {0.f, 0.f, 0.f, 0.f};
      if (node < NN) v = ((const float4*)x)[(size_t)node * 16 + c];
      pack4(v, &Xbuf[e][c * 4]);
    }
    if (tid < 128) cbuf[tid] = (nb + tid < NN) ? cnt[nb + tid] : 0.0f;
    __syncthreads();

    f32x4 acc[4][4];
#pragma unroll
    for (int rt = 0; rt < 4; rt++)
#pragma unroll
      for (int ct = 0; ct < 4; ct++) acc[rt][ct] = (f32x4){0.f, 0.f, 0.f, 0.f};
#pragma unroll
    for (int ks = 0; ks < 4; ks++) {
      s16x8 af[4];
#pragma unroll
      for (int rt = 0; rt < 4; rt++)
        af[rt] = *(const s16x8*)&Abuf[rowbase + rt * 16 + l15][ks * 32 + quad * 8];
      s16x8 bfr[4];
#pragma unroll
      for (int ct = 0; ct < 4; ct++)
        bfr[ct] = *(const s16x8*)(W2pT + (colbase + ct * 16 + l15) * 128 + ks * 32 + quad * 8);
#pragma unroll
      for (int rt = 0; rt < 4; rt++)
#pragma unroll
        for (int ct = 0; ct < 4; ct++)
          acc[rt][ct] = __builtin_amdgcn_mfma_f32_16x16x32_bf16(af[rt], bfr[ct], acc[rt][ct], 0, 0, 0);
    }
    __syncthreads();
#pragma unroll
    for (int rt = 0; rt < 4; rt++)
#pragma unroll
      for (int r = 0; r < 4; r++) {
        int er = rowbase + rt * 16 + quad * 4 + r;
#pragma unroll
        for (int ct = 0; ct < 4; ct++) {
          float val = acc[rt][ct][r] + cbuf[er] * vj[ct];
          Abuf[er][colbase + ct * 16 + l15] = f2bf(val);
        }
      }
    __syncthreads();

    f32x4 acc2[4][4];
#pragma unroll
    for (int rt = 0; rt < 4; rt++)
#pragma unroll
      for (int ct = 0; ct < 4; ct++) acc2[rt][ct] = (f32x4){0.f, 0.f, 0.f, 0.f};
#pragma unroll
    for (int ks = 0; ks < 6; ks++) {
      s16x8 af[4];
      if (ks < 2) {
#pragma unroll
        for (int rt = 0; rt < 4; rt++)
          af[rt] = *(const s16x8*)&Xbuf[rowbase + rt * 16 + l15][ks * 32 + quad * 8];
      } else {
#pragma unroll
        for (int rt = 0; rt < 4; rt++)
          af[rt] = *(const s16x8*)&Abuf[rowbase + rt * 16 + l15][(ks - 2) * 32 + quad * 8];
      }
      s16x8 bfr[4];
#pragma unroll
      for (int ct = 0; ct < 4; ct++)
        bfr[ct] = *(const s16x8*)(W3bT + (size_t)(colbase + ct * 16 + l15) * 192 + ks * 32 + quad * 8);
#pragma unroll
      for (int rt = 0; rt < 4; rt++)
#pragma unroll
        for (int ct = 0; ct < 4; ct++)
          acc2[rt][ct] = __builtin_amdgcn_mfma_f32_16x16x32_bf16(af[rt], bfr[ct], acc2[rt][ct], 0, 0, 0);
    }

#pragma unroll
    for (int rt = 0; rt < 4; rt++)
#pragma unroll
      for (int r = 0; r < 4; r++) {
        int er = rowbase + rt * 16 + quad * 4 + r;
        int node = nb + er;
        if (node < NN) {
#pragma unroll
          for (int ct = 0; ct < 4; ct++) {
            float val = acc2[rt][ct][r] + b3j[ct];
            val = val > 0.0f ? val : 0.01f * val;
            lsum[ct] += val; lsq[ct] += val * val;
            tOut[(size_t)node * 128 + colbase + ct * 16 + l15] = f2bf(val);
          }
        }
      }
  }

  sred[tid] = 0.0f;
  __syncthreads();
#pragma unroll
  for (int ct = 0; ct < 4; ct++) {
    float s = lsum[ct], q = lsq[ct];
    s += __shfl_down(s, 32); q += __shfl_down(q, 32);
    s += __shfl_down(s, 16); q += __shfl_down(q, 16);
    if (lane < 16) {
      atomicAdd(&sred[colbase + ct * 16 + l15], s);
      atomicAdd(&sred[128 + colbase + ct * 16 + l15], q);
    }
  }
  __syncthreads();
  atomicAdd(&stat2[tid], sred[tid]);
}

// ---------------------------------------------------------------- K5: fold BN2 into W4
__global__ void k5_fold2(const float* __restrict__ stat2, const float* __restrict__ g2,
                         const float* __restrict__ be2, const float* __restrict__ W4,
                         const float* __restrict__ b4,
                         unsigned short* __restrict__ W4fT, float* __restrict__ b4f) {
  __shared__ float s2s[128], t2s[128];
  __shared__ float red[256];
  const int tid = threadIdx.x;
  if (tid < 128) {
    float mean = stat2[tid] * (1.0f / NN);
    float var = stat2[128 + tid] * (1.0f / NN) - mean * mean;
    float rstd = rsqrtf(var + 1e-5f);
    float s = g2[tid] * rstd;
    s2s[tid] = s; t2s[tid] = be2[tid] - mean * s;
  }
  __syncthreads();
  const int b = blockIdx.x;
  if (b < 8) {
#pragma unroll
    for (int j = 0; j < 4; j++) {
      int i = b * 1024 + j * 256 + tid;          // i indexes W4 [k][n] row-major, n<64
      int k = i >> 6, n = i & 63;
      W4fT[n * 128 + k] = f2bf(s2s[k] * W4[i]);
    }
  } else {
    int j = tid & 63, part = tid >> 6;
    float p = 0.f;
    for (int k = part * 32; k < part * 32 + 32; k++) p += t2s[k] * W4[k * 64 + j];
    red[tid] = p;
    __syncthreads();
    if (tid < 64) b4f[tid] = red[tid] + red[tid + 64] + red[tid + 128] + red[tid + 192] + b4[tid];
  }
}

// ---------------------------------------------------------------- K6: out = t @ W4f + b4f
__global__ __launch_bounds__(256, 2) void k6_out(
    const unsigned short* __restrict__ tIn, const unsigned short* __restrict__ W4fT,
    const float* __restrict__ b4f, float* __restrict__ out) {
  __shared__ unsigned short Abuf[128][136];
  const int tid = threadIdx.x;
  const int wave = tid >> 6, lane = tid & 63;
  const int l15 = lane & 15, quad = lane >> 4;
  const int rowbase = (wave >> 1) * 64;
  const int colbase = (wave & 1) * 32;

  s16x8 bfrag[2][4];
#pragma unroll
  for (int ct = 0; ct < 2; ct++)
#pragma unroll
    for (int ks = 0; ks < 4; ks++)
      bfrag[ct][ks] = *(const s16x8*)(W4fT + (colbase + ct * 16 + l15) * 128 + ks * 32 + quad * 8);
  float bj[2];
#pragma unroll
  for (int ct = 0; ct < 2; ct++) bj[ct] = b4f[colbase + ct * 16 + l15];

  for (int t = blockIdx.x; t < NTILE_N; t += gridDim.x) {
    const int nb = t * 128;
    __syncthreads();
#pragma unroll
    for (int i = 0; i < 8; i++) {
      int idx = tid + i * 256; int e = idx >> 4, c = idx & 15;
      int node = nb + e;
      s16x8 v = {0, 0, 0, 0, 0, 0, 0, 0};
      if (node < NN) v = *(const s16x8*)(tIn + (size_t)node * 128 + c * 8);
      *(s16x8*)&Abuf[e][c * 8] = v;
    }
    __syncthreads();

    f32x4 acc[4][2];
#pragma unroll
    for (int rt = 0; rt < 4; rt++)
#pragma unroll
      for (int ct = 0; ct < 2; ct++) acc[rt][ct] = (f32x4){0.f, 0.f, 0.f, 0.f};
#pragma unroll
    for (int ks = 0; ks < 4; ks++) {
      s16x8 af[4];
#pragma unroll
      for (int rt = 0; rt < 4; rt++)
        af[rt] = *(const s16x8*)&Abuf[rowbase + rt * 16 + l15][ks * 32 + quad * 8];
#pragma unroll
      for (int rt = 0; rt < 4; rt++)
#pragma unroll
        for (int ct = 0; ct < 2; ct++)
          acc[rt][ct] = __builtin_amdgcn_mfma_f32_16x16x32_bf16(af[rt], bfrag[ct][ks], acc[rt][ct], 0, 0, 0);
    }
#pragma unroll
    for (int rt = 0; rt < 4; rt++)
#pragma unroll
      for (int r = 0; r < 4; r++) {
        int er = rowbase + rt * 16 + quad * 4 + r;
        int node = nb + er;
        if (node < NN) {
#pragma unroll
          for (int ct = 0; ct < 2; ct++)
            out[(size_t)node * 64 + colbase + ct * 16 + l15] = acc[rt][ct][r] + bj[ct];
        }
      }
  }
}

// ---------------------------------------------------------------- launch
extern "C" void kernel_launch(void* const* d_in, const int* in_sizes, int n_in,
                              void* d_out, int out_size, void* d_ws, size_t ws_size,
                              hipStream_t stream) {
  (void)in_sizes; (void)n_in; (void)out_size; (void)ws_size;
  const float* x   = (const float*)d_in[0];
  const int*   ei  = (const int*)d_in[1];
  const float* ea  = (const float*)d_in[2];
  const float* W1  = (const float*)d_in[5];
  const float* b1  = (const float*)d_in[6];
  const float* g1  = (const float*)d_in[7];
  const float* be1 = (const float*)d_in[8];
  const float* W2  = (const float*)d_in[9];
  const float* b2  = (const float*)d_in[10];
  const float* W3  = (const float*)d_in[11];
  const float* b3  = (const float*)d_in[12];
  const float* g2  = (const float*)d_in[13];
  const float* be2 = (const float*)d_in[14];
  const float* W4  = (const float*)d_in[15];
  const float* b4  = (const float*)d_in[16];
  float* out = (float*)d_out;

  char* w = (char*)d_ws;
  float* S     = (float*)(w);                              // 51,200,000
  float* stat1 = (float*)(w + 51200000);                   //      1,024
  float* stat2 = (float*)(w + 51201024);                   //      1,024
  int*   hist  = (int*)  (w + 51202048);                   //    400,384  (also off[])
  float* cntF  = (float*)(w + 51602432);                   //    400,384
  unsigned short* W1bT = (unsigned short*)(w + 52002816);  //     32,768
  unsigned short* W3bT = (unsigned short*)(w + 52035584);  //     49,152
  unsigned short* W2pT = (unsigned short*)(w + 52084736);  //     32,768
  float* v128  = (float*)(w + 52117504);                   //        512
  unsigned short* W4fT = (unsigned short*)(w + 52118016);  //     16,384
  float* b4f   = (float*)(w + 52134400);                   //        256
  unsigned short* tOut = (unsigned short*)(w + 52134656);  // 25,600,000
  // pairS (12.8 MB, int2 {col,e}) aliases tOut's space — lifetimes disjoint (sort+k1 vs k3+k6)
  int2* pairS = (int2*)(w + 52134656);                     // 12,800,000
  // total ws use: 77,734,656 B

  hipMemsetAsync(d_ws, 0, 51602432, stream);   // zero S + stat1 + stat2 + hist

  k0_prep<<<160, 256, 0, stream>>>(W1, W3, W1bT, W3bT);
  k_hist<<<6250, 256, 0, stream>>>(ei, hist);
  k_scan<<<1, 1024, 0, stream>>>(hist, cntF);
  k_scatter<<<6250, 256, 0, stream>>>(ei, hist, pairS);
  k1_edge<<<512, 512, 0, stream>>>(x, ei, ea, W1bT, b1, pairS, S, stat1);
  k2_fold1<<<17, 256, 0, stream>>>(stat1, g1, be1, W2, b2, W2pT, v128);
  k3_node<<<512, 256, 0, stream>>>(x, S, cntF, W2pT, v128, W3bT, b3, tOut, stat2);
  k5_fold2<<<9, 256, 0, stream>>>(stat2, g2, be2, W4, b4, W4fT, b4f);
  k6_out<<<512, 256, 0, stream>>>(tOut, W4fT, b4f, out);
}